// Round 4
// baseline (155.614 us; speedup 1.0000x reference)
//
#include <hip/hip_runtime.h>

#define DEV __device__ __forceinline__

typedef __bf16 bf16x8 __attribute__((ext_vector_type(8)));
typedef unsigned short u16x8v __attribute__((ext_vector_type(8)));
typedef float f32x4 __attribute__((ext_vector_type(4)));
typedef float f32x16 __attribute__((ext_vector_type(16)));
typedef unsigned int u32x4v __attribute__((ext_vector_type(4)));
typedef unsigned short u16;
typedef unsigned int u32;

// f32 -> bf16 bits, round-to-nearest-even
DEV u16 f2bf(float f) {
    u32 u = __builtin_bit_cast(u32, f);
    u = (u + 0x7FFFu + ((u >> 16) & 1u)) >> 16;
    return (u16)u;
}

DEV bf16x8 ld_bf8(const u16* p) {
    return *reinterpret_cast<const bf16x8*>(p);
}

// pack two f32 -> one u32 of 2 bf16 (lo = a, hi = b)
DEV u32 cvt_pk_bf16(float a, float b) {
    u32 r;
    asm("v_cvt_pk_bf16_f32 %0, %1, %2" : "=v"(r) : "v"(a), "v"(b));
    return r;
}

// ---------------------------------------------------------------------------
// Kernel 1: prep.  Blocks [0,384): weight transpose+convert (Wq pre-scaled by
// 1/sqrt(512)*log2(e)).  Blocks [384,4480): x f32 -> bf16.
// ---------------------------------------------------------------------------
__global__ __launch_bounds__(256) void prep_kernel(const float* __restrict__ x,
                                                   const float* __restrict__ W0,
                                                   const float* __restrict__ W1,
                                                   const float* __restrict__ W2,
                                                   u16* __restrict__ Wt,
                                                   u16* __restrict__ xb) {
    const int blk = blockIdx.x;
    if (blk < 384) {
        int idx = blk * 256 + threadIdx.x;   // 3*64*512 = 98304
        int w = idx >> 15, rem = idx & 32767, h = rem >> 9, c = rem & 511;
        const float* W = (w == 0) ? W0 : ((w == 1) ? W1 : W2);
        float v = W[c * 64 + h];
        if (w == 0) v *= 0.044194173824159216f * 1.4426950408889634f;  // SCL*log2e
        Wt[idx] = f2bf(v);
    } else {
        int i = (blk - 384) * 256 + threadIdx.x;   // < 1048576
        float4 a0 = reinterpret_cast<const float4*>(x)[2 * i];
        float4 a1 = reinterpret_cast<const float4*>(x)[2 * i + 1];
        u16x8v o;
        o[0] = f2bf(a0.x); o[1] = f2bf(a0.y); o[2] = f2bf(a0.z); o[3] = f2bf(a0.w);
        o[4] = f2bf(a1.x); o[5] = f2bf(a1.y); o[6] = f2bf(a1.z); o[7] = f2bf(a1.w);
        reinterpret_cast<u16x8v*>(xb)[i] = o;
    }
}

// ---------------------------------------------------------------------------
// Kernel 2: QKV projection via MFMA 16x16x32 bf16, reading bf16 xb.
// 768 blocks: mat = blk%3, rowgroup = blk/3. Wave: 16 rows x 64 cols.
// Q (pre-scaled), K row-major bf16; V transposed Vt[b][d][t] bf16.
// ---------------------------------------------------------------------------
__global__ __launch_bounds__(256) void proj_kernel(const u16* __restrict__ xb,
                                                   const u16* __restrict__ Wt,
                                                   u16* __restrict__ Q,
                                                   u16* __restrict__ Kq,
                                                   u16* __restrict__ Vt) {
    const int wave = threadIdx.x >> 6, lane = threadIdx.x & 63;
    const int lr = lane & 15, lg = lane >> 4;
    const int mat = blockIdx.x % 3;
    const int rg = blockIdx.x / 3;
    const int r0 = rg * 64 + wave * 16;
    const int grow = r0 + lr;

    f32x4 acc[4];
#pragma unroll
    for (int b = 0; b < 4; ++b) acc[b] = (f32x4){0.f, 0.f, 0.f, 0.f};

#pragma unroll
    for (int kk = 0; kk < 16; ++kk) {
        bf16x8 af = ld_bf8(xb + (size_t)grow * 512 + kk * 32 + lg * 8);
#pragma unroll
        for (int nt = 0; nt < 4; ++nt) {
            bf16x8 bf = ld_bf8(Wt + mat * 32768 + (lr + 16 * nt) * 512 + kk * 32 + lg * 8);
            acc[nt] = __builtin_amdgcn_mfma_f32_16x16x32_bf16(af, bf, acc[nt], 0, 0, 0);
        }
    }

    if (mat < 2) {
        u16* dst = (mat == 0) ? Q : Kq;
#pragma unroll
        for (int nt = 0; nt < 4; ++nt) {
            const int h = lr + 16 * nt;
#pragma unroll
            for (int reg = 0; reg < 4; ++reg)
                dst[(size_t)(r0 + 4 * lg + reg) * 64 + h] = f2bf(acc[nt][reg]);
        }
    } else {
        const int bidx = r0 >> 12;
        const int t0 = (r0 & 4095) + 4 * lg;
#pragma unroll
        for (int nt = 0; nt < 4; ++nt) {
            const int h = lr + 16 * nt;
            ushort4 hv;
            hv.x = f2bf(acc[nt][0]); hv.y = f2bf(acc[nt][1]);
            hv.z = f2bf(acc[nt][2]); hv.w = f2bf(acc[nt][3]);
            *reinterpret_cast<ushort4*>(Vt + ((size_t)(bidx * 64 + h)) * 4096 + t0) = hv;
        }
    }
}

// ---------------------------------------------------------------------------
// Kernel 3: causal flash attention, swapped-operand 32x32, zero LDS.
// Per wave: 32 q-rows, iterate 32-key tiles.  S^T = mfma(K,Q): lane owns
// q-col = lane&31, 16 k-rows crow = (reg&3)+8*(reg>>2)+4*(lane>>5).
// O^T = mfma(V^T, P^T): lane owns q-col again -> softmax state is lane-local.
// Partials written transposed: Opart[tile*SPLIT+c][d][q].
// ---------------------------------------------------------------------------
__global__ __launch_bounds__(256) void attn_part_kernel(const u16* __restrict__ Q,
                                                        const u16* __restrict__ K,
                                                        const u16* __restrict__ Vt,
                                                        float* __restrict__ Opart,
                                                        float* __restrict__ Mpart,
                                                        float* __restrict__ Lpart,
                                                        int SPLIT, int CT) {
    const int lane = threadIdx.x & 63, wave = threadIdx.x >> 6;
    const int q31 = lane & 31, hi = lane >> 5;
    const int gid = blockIdx.x * 4 + wave;
    const int tile = gid & 511, c = gid >> 9;
    const int b = tile >> 7, qi = tile & 127;
    const int qr0 = qi * 32;
    const int nkv = qi + 1;                  // 32-key tiles for this q-tile
    const int it0 = c * CT;
    if (it0 >= nkv) return;
    const int it1 = min(nkv, it0 + CT);

    const u16* Qb = Q + (size_t)b * 4096 * 64;
    const u16* Kb = K + (size_t)b * 4096 * 64;
    const u16* Vb = Vt + (size_t)b * 64 * 4096;

    // Q fragments (B-operand): lane holds Q[qr0+q31][kk*16 + hi*8 + j]
    bf16x8 qf[4];
#pragma unroll
    for (int kk = 0; kk < 4; ++kk)
        qf[kk] = ld_bf8(Qb + (size_t)(qr0 + q31) * 64 + kk * 16 + hi * 8);

    f32x16 o0, o1;
#pragma unroll
    for (int r = 0; r < 16; ++r) { o0[r] = 0.f; o1[r] = 0.f; }
    float m_run = -1.0e30f, l_run = 0.f;

    for (int it = it0; it < it1; ++it) {
        const int kv0 = it * 32;

        // S^T = K . Q^T   (32 keys x 32 q), A = K fragments
        f32x16 st;
#pragma unroll
        for (int r = 0; r < 16; ++r) st[r] = 0.f;
#pragma unroll
        for (int kk = 0; kk < 4; ++kk) {
            bf16x8 kf = ld_bf8(Kb + (size_t)(kv0 + q31) * 64 + kk * 16 + hi * 8);
            st = __builtin_amdgcn_mfma_f32_32x32x16_bf16(kf, qf[kk], st, 0, 0, 0);
        }

        // causal mask: only the diagonal tile (kv0 == qr0); crow > q31 => masked
        if (it == nkv - 1) {
#pragma unroll
            for (int reg = 0; reg < 16; ++reg) {
                const int crow = (reg & 3) + 8 * (reg >> 2) + 4 * hi;
                if (crow > q31) st[reg] = -3.0e38f;
            }
        }

        // per-q max: in-lane tree over 16 regs + half-swap
        float pm = st[0];
#pragma unroll
        for (int reg = 1; reg < 16; ++reg) pm = fmaxf(pm, st[reg]);
        pm = fmaxf(pm, __shfl_xor(pm, 32, 64));

        // defer-rescale (THR = 11.5 in log2 units ~ 8 nats)
        if (!__all(pm - m_run <= 11.5f)) {
            float mn = fmaxf(m_run, pm);
            float al = exp2f(m_run - mn);
            m_run = mn;
            l_run *= al;
#pragma unroll
            for (int r = 0; r < 16; ++r) { o0[r] *= al; o1[r] *= al; }
        }

        // P = exp2(S - m), row sum (scores already in log2 domain via Wq scale)
        float rs = 0.f;
#pragma unroll
        for (int reg = 0; reg < 16; ++reg) {
            float p = exp2f(st[reg] - m_run);
            st[reg] = p;
            rs += p;
        }
        rs += __shfl_xor(rs, 32, 64);
        l_run += rs;

        // pack P^T into B-fragments for the two PV k-steps.
        // own packed words A_w = (p[2w], p[2w+1]) hold keys (wk, wk+1) where
        // wk = (2w&3)+8*(w>>1)+4*hi ... enumerated: A0:k{0,1}+4hi A1:k{2,3}+4hi
        // A2:k{8,9}+4hi A3:k{10,11}+4hi A4..A7: +16.
        u32 A[8], S[8];
#pragma unroll
        for (int w = 0; w < 8; ++w) A[w] = cvt_pk_bf16(st[2 * w], st[2 * w + 1]);
#pragma unroll
        for (int w = 0; w < 8; ++w) S[w] = __shfl_xor(A[w], 32, 64);

        // ks=0 needs k = 8*hi + 0..7 ; ks=1 needs k = 16 + 8*hi + 0..7
        u32x4v pw0, pw1;
        pw0[0] = hi ? S[2] : A[0];
        pw0[1] = hi ? S[3] : A[1];
        pw0[2] = hi ? A[2] : S[0];
        pw0[3] = hi ? A[3] : S[1];
        pw1[0] = hi ? S[6] : A[4];
        pw1[1] = hi ? S[7] : A[5];
        pw1[2] = hi ? A[6] : S[4];
        pw1[3] = hi ? A[7] : S[5];
        bf16x8 pb0 = __builtin_bit_cast(bf16x8, pw0);
        bf16x8 pb1 = __builtin_bit_cast(bf16x8, pw1);

        // O^T += V^T . P^T : A = V^T rows (from Vt), B = P^T
        bf16x8 v00 = ld_bf8(Vb + (size_t)q31 * 4096 + kv0 + hi * 8);
        bf16x8 v01 = ld_bf8(Vb + (size_t)q31 * 4096 + kv0 + 16 + hi * 8);
        bf16x8 v10 = ld_bf8(Vb + (size_t)(32 + q31) * 4096 + kv0 + hi * 8);
        bf16x8 v11 = ld_bf8(Vb + (size_t)(32 + q31) * 4096 + kv0 + 16 + hi * 8);
        o0 = __builtin_amdgcn_mfma_f32_32x32x16_bf16(v00, pb0, o0, 0, 0, 0);
        o0 = __builtin_amdgcn_mfma_f32_32x32x16_bf16(v01, pb1, o0, 0, 0, 0);
        o1 = __builtin_amdgcn_mfma_f32_32x32x16_bf16(v10, pb0, o1, 0, 0, 0);
        o1 = __builtin_amdgcn_mfma_f32_32x32x16_bf16(v11, pb1, o1, 0, 0, 0);
    }

    // write transposed partials: Opart[base][d][q]
    const size_t base = (size_t)(tile * SPLIT + c);
    float* Op = Opart + base * 2048;
#pragma unroll
    for (int reg = 0; reg < 16; ++reg) {
        const int crow = (reg & 3) + 8 * (reg >> 2) + 4 * hi;
        Op[crow * 32 + q31] = o0[reg];
        Op[(32 + crow) * 32 + q31] = o1[reg];
    }
    if (lane < 32) {
        Mpart[base * 32 + lane] = m_run;
        Lpart[base * 32 + lane] = l_run;
    }
}

// ---------------------------------------------------------------------------
// Kernel 4: merge partials.  One thread per output element (t_glob, h).
// Reads transposed Opart[base][h][q]; m already in log2 domain.
// ---------------------------------------------------------------------------
__global__ __launch_bounds__(256) void merge_kernel(const float* __restrict__ Opart,
                                                    const float* __restrict__ Mpart,
                                                    const float* __restrict__ Lpart,
                                                    float* __restrict__ out,
                                                    int SPLIT, int CT) {
    const int idx = blockIdx.x * 256 + threadIdx.x;    // < 1048576
    const int h = idx & 63;
    const int tg = idx >> 6;
    const int tile = tg >> 5, qrow = tg & 31;
    const int qi = tile & 127;
    const int nkv = qi + 1;
    int nc = (nkv + CT - 1) / CT;
    if (nc > SPLIT) nc = SPLIT;

    float M = -3.0e38f;
    for (int c = 0; c < nc; ++c)
        M = fmaxf(M, Mpart[(tile * SPLIT + c) * 32 + qrow]);
    float L = 0.f, acc = 0.f;
    for (int c = 0; c < nc; ++c) {
        const size_t base = (size_t)(tile * SPLIT + c);
        float w = exp2f(Mpart[base * 32 + qrow] - M);
        L += w * Lpart[base * 32 + qrow];
        acc += w * Opart[base * 2048 + h * 32 + qrow];
    }
    out[(size_t)tg * 64 + h] = acc / L;
}

// ---------------------------------------------------------------------------
extern "C" void kernel_launch(void* const* d_in, const int* in_sizes, int n_in,
                              void* d_out, int out_size, void* d_ws, size_t ws_size,
                              hipStream_t stream) {
    const float* x  = (const float*)d_in[0];
    const float* Wq = (const float*)d_in[1];
    const float* Wk = (const float*)d_in[2];
    const float* Wv = (const float*)d_in[3];
    float* out = (float*)d_out;

    char* ws = (char*)d_ws;
    const size_t MB = 1024 * 1024;
    u16* Qw  = (u16*)(ws);                     // 2 MiB
    u16* Kw  = (u16*)(ws + 2 * MB);            // 2 MiB
    u16* Vtw = (u16*)(ws + 4 * MB);            // 2 MiB
    u16* Wt  = (u16*)(ws + 6 * MB);            // 96 KiB

    // partials at 8MB: Opart SPLIT*4MB, then M/L SPLIT*64KB each.
    // xb (16MB) aliases Opart when SPLIT>=4 (lifetimes stream-ordered disjoint),
    // else placed after Lpart.
    int SPLIT = 16;
    while (SPLIT > 1) {
        size_t need = 8 * MB + (size_t)SPLIT * 4 * MB + (size_t)SPLIT * 128 * 1024 +
                      ((SPLIT >= 4) ? 0 : 16 * MB);
        if (need <= ws_size) break;
        SPLIT >>= 1;
    }
    const int CT = (128 + SPLIT - 1) / SPLIT;

    float* Opart = (float*)(ws + 8 * MB);
    float* Mpart = (float*)(ws + 8 * MB + (size_t)SPLIT * 4 * MB);
    float* Lpart = Mpart + (size_t)SPLIT * 512 * 32;
    u16* xb = (SPLIT >= 4) ? (u16*)(ws + 8 * MB)
                           : (u16*)((char*)Lpart + (size_t)SPLIT * 64 * 1024);

    prep_kernel<<<4480, 256, 0, stream>>>(x, Wq, Wk, Wv, Wt, xb);
    proj_kernel<<<768, 256, 0, stream>>>(xb, Wt, Qw, Kw, Vtw);
    attn_part_kernel<<<128 * SPLIT, 256, 0, stream>>>(Qw, Kw, Vtw, Opart, Mpart, Lpart,
                                                      SPLIT, CT);
    merge_kernel<<<4096, 256, 0, stream>>>(Opart, Mpart, Lpart, out, SPLIT, CT);
}

// Round 6
// 108.090 us; speedup vs baseline: 1.4397x; 1.4397x over previous
//
#include <hip/hip_runtime.h>

#define DEV __device__ __forceinline__

typedef __bf16 bf16x8 __attribute__((ext_vector_type(8)));
typedef unsigned short u16x8v __attribute__((ext_vector_type(8)));
typedef float f32x4 __attribute__((ext_vector_type(4)));
typedef float f32x16 __attribute__((ext_vector_type(16)));
typedef unsigned int u32x4v __attribute__((ext_vector_type(4)));
typedef unsigned short u16;
typedef unsigned int u32;

// f32 -> bf16 bits, round-to-nearest-even
DEV u16 f2bf(float f) {
    u32 u = __builtin_bit_cast(u32, f);
    u = (u + 0x7FFFu + ((u >> 16) & 1u)) >> 16;
    return (u16)u;
}

DEV bf16x8 ld_bf8(const u16* p) {
    return *reinterpret_cast<const bf16x8*>(p);
}

// pack two f32 -> one u32 of 2 bf16 (lo = a, hi = b)
DEV u32 cvt_pk_bf16(float a, float b) {
    u32 r;
    asm("v_cvt_pk_bf16_f32 %0, %1, %2" : "=v"(r) : "v"(a), "v"(b));
    return r;
}

// ---------------------------------------------------------------------------
// Kernel 1: prep.  Blocks [0,384): weight transpose+convert (Wq pre-scaled by
// 1/sqrt(512)*log2(e)).  Blocks [384,4480): x f32 -> bf16.
// ---------------------------------------------------------------------------
__global__ __launch_bounds__(256) void prep_kernel(const float* __restrict__ x,
                                                   const float* __restrict__ W0,
                                                   const float* __restrict__ W1,
                                                   const float* __restrict__ W2,
                                                   u16* __restrict__ Wt,
                                                   u16* __restrict__ xb) {
    const int blk = blockIdx.x;
    if (blk < 384) {
        int idx = blk * 256 + threadIdx.x;   // 3*64*512 = 98304
        int w = idx >> 15, rem = idx & 32767, h = rem >> 9, c = rem & 511;
        const float* W = (w == 0) ? W0 : ((w == 1) ? W1 : W2);
        float v = W[c * 64 + h];
        if (w == 0) v *= 0.044194173824159216f * 1.4426950408889634f;  // SCL*log2e
        Wt[idx] = f2bf(v);
    } else {
        int i = (blk - 384) * 256 + threadIdx.x;   // < 1048576
        float4 a0 = reinterpret_cast<const float4*>(x)[2 * i];
        float4 a1 = reinterpret_cast<const float4*>(x)[2 * i + 1];
        u16x8v o;
        o[0] = f2bf(a0.x); o[1] = f2bf(a0.y); o[2] = f2bf(a0.z); o[3] = f2bf(a0.w);
        o[4] = f2bf(a1.x); o[5] = f2bf(a1.y); o[6] = f2bf(a1.z); o[7] = f2bf(a1.w);
        reinterpret_cast<u16x8v*>(xb)[i] = o;
    }
}

// ---------------------------------------------------------------------------
// Kernel 2: QKV projection via MFMA 16x16x32 bf16, reading bf16 xb.
// 768 blocks: mat = blk%3, rowgroup = blk/3. Wave: 16 rows x 64 cols.
// ---------------------------------------------------------------------------
__global__ __launch_bounds__(256) void proj_kernel(const u16* __restrict__ xb,
                                                   const u16* __restrict__ Wt,
                                                   u16* __restrict__ Q,
                                                   u16* __restrict__ Kq,
                                                   u16* __restrict__ Vt) {
    const int wave = threadIdx.x >> 6, lane = threadIdx.x & 63;
    const int lr = lane & 15, lg = lane >> 4;
    const int mat = blockIdx.x % 3;
    const int rg = blockIdx.x / 3;
    const int r0 = rg * 64 + wave * 16;
    const int grow = r0 + lr;

    f32x4 acc[4];
#pragma unroll
    for (int b = 0; b < 4; ++b) acc[b] = (f32x4){0.f, 0.f, 0.f, 0.f};

#pragma unroll
    for (int kk = 0; kk < 16; ++kk) {
        bf16x8 af = ld_bf8(xb + (size_t)grow * 512 + kk * 32 + lg * 8);
#pragma unroll
        for (int nt = 0; nt < 4; ++nt) {
            bf16x8 bf = ld_bf8(Wt + mat * 32768 + (lr + 16 * nt) * 512 + kk * 32 + lg * 8);
            acc[nt] = __builtin_amdgcn_mfma_f32_16x16x32_bf16(af, bf, acc[nt], 0, 0, 0);
        }
    }

    if (mat < 2) {
        u16* dst = (mat == 0) ? Q : Kq;
#pragma unroll
        for (int nt = 0; nt < 4; ++nt) {
            const int h = lr + 16 * nt;
#pragma unroll
            for (int reg = 0; reg < 4; ++reg)
                dst[(size_t)(r0 + 4 * lg + reg) * 64 + h] = f2bf(acc[nt][reg]);
        }
    } else {
        const int bidx = r0 >> 12;
        const int t0 = (r0 & 4095) + 4 * lg;
#pragma unroll
        for (int nt = 0; nt < 4; ++nt) {
            const int h = lr + 16 * nt;
            ushort4 hv;
            hv.x = f2bf(acc[nt][0]); hv.y = f2bf(acc[nt][1]);
            hv.z = f2bf(acc[nt][2]); hv.w = f2bf(acc[nt][3]);
            *reinterpret_cast<ushort4*>(Vt + ((size_t)(bidx * 64 + h)) * 4096 + t0) = hv;
        }
    }
}

// ---------------------------------------------------------------------------
// Attention helpers (32x32 swapped-operand pieces)
// ---------------------------------------------------------------------------
DEV f32x16 qk_sub(const u16* kp, const bf16x8 (&qf)[4]) {
    f32x16 st;
#pragma unroll
    for (int r = 0; r < 16; ++r) st[r] = 0.f;
#pragma unroll
    for (int kk = 0; kk < 4; ++kk)
        st = __builtin_amdgcn_mfma_f32_32x32x16_bf16(ld_bf8(kp + kk * 16), qf[kk], st, 0, 0, 0);
    return st;
}

DEV void mask_diag(f32x16& st, int q31, int hi) {
#pragma unroll
    for (int reg = 0; reg < 16; ++reg) {
        const int crow = (reg & 3) + 8 * (reg >> 2) + 4 * hi;
        if (crow > q31) st[reg] = -3.0e38f;
    }
}

// pairwise max tree over 16 regs (depth 4)
DEV float max16(const f32x16& a) {
    float t[8];
#pragma unroll
    for (int i = 0; i < 8; ++i) t[i] = fmaxf(a[i], a[i + 8]);
    float u0 = fmaxf(t[0], t[4]), u1 = fmaxf(t[1], t[5]);
    float u2 = fmaxf(t[2], t[6]), u3 = fmaxf(t[3], t[7]);
    return fmaxf(fmaxf(u0, u1), fmaxf(u2, u3));
}

// st = exp2(st - m); returns 4-chain partial sum
DEV float expsum(f32x16& st, float m) {
    float r0 = 0.f, r1 = 0.f, r2 = 0.f, r3 = 0.f;
#pragma unroll
    for (int g = 0; g < 4; ++g) {
        float p0 = exp2f(st[4 * g + 0] - m);
        float p1 = exp2f(st[4 * g + 1] - m);
        float p2 = exp2f(st[4 * g + 2] - m);
        float p3 = exp2f(st[4 * g + 3] - m);
        st[4 * g + 0] = p0; st[4 * g + 1] = p1;
        st[4 * g + 2] = p2; st[4 * g + 3] = p3;
        r0 += p0; r1 += p1; r2 += p2; r3 += p3;
    }
    return (r0 + r1) + (r2 + r3);
}

// P^T registers -> two B-fragments for PV.  8 cvt_pk + 4 shfl_xor + selects.
// B-fragment key map (per lane: q = lane&31, hi = lane>>5):
//   pb0 word w holds keys (hi*8 + 2w, hi*8 + 2w+1); pb1 same +16.
// Own cvt_pk words: A_w = keys ((2w&3) + 8*(w>>1) + 4*hi, +1).
//   hi=0: pb0 = {A0, A1, pA0, pA1};  hi=1: pb0 = {pA2, pA3, A2, A3}
//   hi=0: pb1 = {A4, A5, pA4, pA5};  hi=1: pb1 = {pA6, pA7, A6, A7}
// (p = partner lane, lane^32).  Select-then-exchange: one shuffle serves
// word2@hi=0 and word0@hi=1 simultaneously.
DEV void packP(const f32x16& st, bf16x8& pb0, bf16x8& pb1, int hi) {
    u32 A0 = cvt_pk_bf16(st[0], st[1]),  A1 = cvt_pk_bf16(st[2], st[3]);
    u32 A2 = cvt_pk_bf16(st[4], st[5]),  A3 = cvt_pk_bf16(st[6], st[7]);
    u32 A4 = cvt_pk_bf16(st[8], st[9]),  A5 = cvt_pk_bf16(st[10], st[11]);
    u32 A6 = cvt_pk_bf16(st[12], st[13]), A7 = cvt_pk_bf16(st[14], st[15]);
    u32 e0 = __shfl_xor(hi ? A0 : A2, 32, 64);   // hi=0 gets pA0; hi=1 gets pA2
    u32 e1 = __shfl_xor(hi ? A1 : A3, 32, 64);   // hi=0 gets pA1; hi=1 gets pA3
    u32 e2 = __shfl_xor(hi ? A4 : A6, 32, 64);   // hi=0 gets pA4; hi=1 gets pA6
    u32 e3 = __shfl_xor(hi ? A5 : A7, 32, 64);   // hi=0 gets pA5; hi=1 gets pA7
    u32x4v w0, w1;
    w0[0] = hi ? e0 : A0;
    w0[1] = hi ? e1 : A1;
    w0[2] = hi ? A2 : e0;
    w0[3] = hi ? A3 : e1;
    w1[0] = hi ? e2 : A4;
    w1[1] = hi ? e3 : A5;
    w1[2] = hi ? A6 : e2;
    w1[3] = hi ? A7 : e3;
    pb0 = __builtin_bit_cast(bf16x8, w0);
    pb1 = __builtin_bit_cast(bf16x8, w1);
}

DEV void pv(const u16* vp, const bf16x8& pb0, const bf16x8& pb1,
            f32x16& o0, f32x16& o1) {
    bf16x8 v00 = ld_bf8(vp);
    bf16x8 v01 = ld_bf8(vp + 16);
    bf16x8 v10 = ld_bf8(vp + 32 * 4096);
    bf16x8 v11 = ld_bf8(vp + 32 * 4096 + 16);
    o0 = __builtin_amdgcn_mfma_f32_32x32x16_bf16(v00, pb0, o0, 0, 0, 0);
    o0 = __builtin_amdgcn_mfma_f32_32x32x16_bf16(v01, pb1, o0, 0, 0, 0);
    o1 = __builtin_amdgcn_mfma_f32_32x32x16_bf16(v10, pb0, o1, 0, 0, 0);
    o1 = __builtin_amdgcn_mfma_f32_32x32x16_bf16(v11, pb1, o1, 0, 0, 0);
}

// ---------------------------------------------------------------------------
// Kernel 3: causal flash attention, swapped-operand 32x32, zero LDS,
// 64-key outer iterations (2 independent 32-key chains for ILP).
// Block decode XCD-swizzled: b = blk&3 so each batch pins to 2 XCDs' L2.
// ---------------------------------------------------------------------------
__global__ __launch_bounds__(256) void attn_part_kernel(const u16* __restrict__ Q,
                                                        const u16* __restrict__ K,
                                                        const u16* __restrict__ Vt,
                                                        float* __restrict__ Opart,
                                                        float* __restrict__ Mpart,
                                                        float* __restrict__ Lpart,
                                                        int SPLIT, int CT) {
    const int lane = threadIdx.x & 63, wave = threadIdx.x >> 6;
    const int q31 = lane & 31, hi = lane >> 5;
    const int blk = blockIdx.x;
    const int tg4 = ((blk & 3) << 5) | ((blk >> 2) & 31);   // tile-group (4 tiles)
    const int c = blk >> 7;
    const int tile = tg4 * 4 + wave;          // 0..511; b = tile>>7 = blk&3
    const int b = tile >> 7, qi = tile & 127;
    const int qr0 = qi * 32;
    const int nkv = qi + 1;                   // 32-key subtiles for this q-tile
    const int s0 = c * CT;
    if (s0 >= nkv) return;
    const int s1 = min(nkv, s0 + CT);

    const u16* Qb = Q + (size_t)b * 4096 * 64;
    const u16* Kb = K + (size_t)b * 4096 * 64;
    const u16* Vb = Vt + (size_t)b * 64 * 4096;

    bf16x8 qf[4];
#pragma unroll
    for (int kk = 0; kk < 4; ++kk)
        qf[kk] = ld_bf8(Qb + (size_t)(qr0 + q31) * 64 + kk * 16 + hi * 8);

    f32x16 o0, o1;
#pragma unroll
    for (int r = 0; r < 16; ++r) { o0[r] = 0.f; o1[r] = 0.f; }
    float m_run = -1.0e30f, l_run = 0.f;

    for (int s = s0; s < s1; s += 2) {
        const int kv0 = s * 32;
        const bool hasB = (s + 1 < s1);
        const u16* kpA = Kb + (size_t)(kv0 + q31) * 64 + hi * 8;

        f32x16 stA = qk_sub(kpA, qf);
        f32x16 stB;
        if (hasB) stB = qk_sub(kpA + 32 * 64, qf);

        if (s == qi) mask_diag(stA, q31, hi);
        if (hasB && s + 1 == qi) mask_diag(stB, q31, hi);

        float pm = hasB ? fmaxf(max16(stA), max16(stB)) : max16(stA);
        pm = fmaxf(pm, __shfl_xor(pm, 32, 64));

        // defer-rescale (THR = 11.5 log2-units)
        if (!__all(pm - m_run <= 11.5f)) {
            float mn = fmaxf(m_run, pm);
            float al = exp2f(m_run - mn);
            m_run = mn;
            l_run *= al;
#pragma unroll
            for (int r = 0; r < 16; ++r) { o0[r] *= al; o1[r] *= al; }
        }

        float rs = expsum(stA, m_run);
        if (hasB) rs += expsum(stB, m_run);
        rs += __shfl_xor(rs, 32, 64);
        l_run += rs;

        const u16* vpA = Vb + (size_t)q31 * 4096 + kv0 + hi * 8;
        bf16x8 p0, p1;
        packP(stA, p0, p1, hi);
        pv(vpA, p0, p1, o0, o1);
        if (hasB) {
            packP(stB, p0, p1, hi);
            pv(vpA + 32, p0, p1, o0, o1);
        }
    }

    // write transposed partials: Opart[base][d][q]  (coalesced: lanes = q)
    const size_t base = (size_t)(tile * SPLIT + c);
    float* Op = Opart + base * 2048;
#pragma unroll
    for (int reg = 0; reg < 16; ++reg) {
        const int crow = (reg & 3) + 8 * (reg >> 2) + 4 * hi;
        Op[crow * 32 + q31] = o0[reg];
        Op[(32 + crow) * 32 + q31] = o1[reg];
    }
    if (lane < 32) {
        Mpart[base * 32 + lane] = m_run;
        Lpart[base * 32 + lane] = l_run;
    }
}

// ---------------------------------------------------------------------------
// Kernel 4: merge partials.  One block per q-tile (512 blocks).
// Chunks staged through LDS: global reads float4-coalesced, LDS pad 33
// breaks bank conflicts, out writes coalesced.
// Thread owns (q = tid>>3, d = (tid&7)*8 .. +7).
// ---------------------------------------------------------------------------
__global__ __launch_bounds__(256) void merge_kernel(const float* __restrict__ Opart,
                                                    const float* __restrict__ Mpart,
                                                    const float* __restrict__ Lpart,
                                                    float* __restrict__ out,
                                                    int SPLIT, int CT) {
    __shared__ float ld[64 * 33];
    const int tile = blockIdx.x;            // 0..511
    const int tid = threadIdx.x;
    const int q = tid >> 3, dg = tid & 7;
    const int qi = tile & 127;
    const int nkv = qi + 1;
    int nc = (nkv + CT - 1) / CT;
    if (nc > SPLIT) nc = SPLIT;

    float M = -3.0e38f;
    for (int c = 0; c < nc; ++c)
        M = fmaxf(M, Mpart[(tile * SPLIT + c) * 32 + q]);

    float L = 0.f;
    float acc[8];
#pragma unroll
    for (int j = 0; j < 8; ++j) acc[j] = 0.f;

    for (int c = 0; c < nc; ++c) {
        const size_t base = (size_t)(tile * SPLIT + c);
        // cooperative coalesced load of the 2048-float chunk -> LDS
        const float4* src = reinterpret_cast<const float4*>(Opart + base * 2048);
        float4 v0 = src[tid * 2];
        float4 v1 = src[tid * 2 + 1];
        {
            const int drow = tid >> 2;           // (tid*8+j)>>5
            const int qq = (tid & 3) * 8;        // (tid*8+j)&31 base
            float* dst = &ld[drow * 33 + qq];
            dst[0] = v0.x; dst[1] = v0.y; dst[2] = v0.z; dst[3] = v0.w;
            dst[4] = v1.x; dst[5] = v1.y; dst[6] = v1.z; dst[7] = v1.w;
        }
        __syncthreads();
        float w = exp2f(Mpart[base * 32 + q] - M);
        L += w * Lpart[base * 32 + q];
#pragma unroll
        for (int j = 0; j < 8; ++j)
            acc[j] += w * ld[(dg * 8 + j) * 33 + q];
        __syncthreads();
    }

    const float inv = 1.0f / L;
    float4 r0, r1;
    r0.x = acc[0] * inv; r0.y = acc[1] * inv; r0.z = acc[2] * inv; r0.w = acc[3] * inv;
    r1.x = acc[4] * inv; r1.y = acc[5] * inv; r1.z = acc[6] * inv; r1.w = acc[7] * inv;
    float4* dst = reinterpret_cast<float4*>(out + ((size_t)(tile * 32 + q)) * 64 + dg * 8);
    dst[0] = r0;
    dst[1] = r1;
}

// ---------------------------------------------------------------------------
extern "C" void kernel_launch(void* const* d_in, const int* in_sizes, int n_in,
                              void* d_out, int out_size, void* d_ws, size_t ws_size,
                              hipStream_t stream) {
    const float* x  = (const float*)d_in[0];
    const float* Wq = (const float*)d_in[1];
    const float* Wk = (const float*)d_in[2];
    const float* Wv = (const float*)d_in[3];
    float* out = (float*)d_out;

    char* ws = (char*)d_ws;
    const size_t MB = 1024 * 1024;
    u16* Qw  = (u16*)(ws);                     // 2 MiB
    u16* Kw  = (u16*)(ws + 2 * MB);            // 2 MiB
    u16* Vtw = (u16*)(ws + 4 * MB);            // 2 MiB
    u16* Wt  = (u16*)(ws + 6 * MB);            // 96 KiB

    int SPLIT = 16;
    while (SPLIT > 1) {
        size_t need = 8 * MB + (size_t)SPLIT * 4 * MB + (size_t)SPLIT * 128 * 1024 +
                      ((SPLIT >= 4) ? 0 : 16 * MB);
        if (need <= ws_size) break;
        SPLIT >>= 1;
    }
    const int CT = (128 + SPLIT - 1) / SPLIT;

    float* Opart = (float*)(ws + 8 * MB);
    float* Mpart = (float*)(ws + 8 * MB + (size_t)SPLIT * 4 * MB);
    float* Lpart = Mpart + (size_t)SPLIT * 512 * 32;
    u16* xb = (SPLIT >= 4) ? (u16*)(ws + 8 * MB)
                           : (u16*)((char*)Lpart + (size_t)SPLIT * 64 * 1024);

    prep_kernel<<<4480, 256, 0, stream>>>(x, Wq, Wk, Wv, Wt, xb);
    proj_kernel<<<768, 256, 0, stream>>>(xb, Wt, Qw, Kw, Vtw);
    attn_part_kernel<<<128 * SPLIT, 256, 0, stream>>>(Qw, Kw, Vtw, Opart, Mpart, Lpart,
                                                      SPLIT, CT);
    merge_kernel<<<512, 256, 0, stream>>>(Opart, Mpart, Lpart, out, SPLIT, CT);
}

// Round 8
// 104.352 us; speedup vs baseline: 1.4912x; 1.0358x over previous
//
#include <hip/hip_runtime.h>

#define DEV __device__ __forceinline__

typedef __bf16 bf16x8 __attribute__((ext_vector_type(8)));
typedef unsigned short u16x8v __attribute__((ext_vector_type(8)));
typedef float f32x4 __attribute__((ext_vector_type(4)));
typedef float f32x16 __attribute__((ext_vector_type(16)));
typedef unsigned int u32x4v __attribute__((ext_vector_type(4)));
typedef unsigned short u16;
typedef unsigned int u32;

// f32 -> bf16 bits, round-to-nearest-even (pure integer ops; validated R1-R6)
DEV u16 f2bf(float f) {
    u32 u = __builtin_bit_cast(u32, f);
    u = (u + 0x7FFFu + ((u >> 16) & 1u)) >> 16;
    return (u16)u;
}

DEV bf16x8 ld_bf8(const u16* p) {
    return *reinterpret_cast<const bf16x8*>(p);
}

// 8 consecutive f32 -> bf16x8 via f2bf (bit-identical to R6's xconv path).
// NOTE: v_cvt_pk_bf16_f32 is deliberately NOT used here — it is only
// validated on non-negative P values (packP); R7 using it on signed x
// failed correctness.
DEV bf16x8 cvt8_rne(float4 a0, float4 a1) {
    u16x8v o;
    o[0] = f2bf(a0.x); o[1] = f2bf(a0.y); o[2] = f2bf(a0.z); o[3] = f2bf(a0.w);
    o[4] = f2bf(a1.x); o[5] = f2bf(a1.y); o[6] = f2bf(a1.z); o[7] = f2bf(a1.w);
    return __builtin_bit_cast(bf16x8, o);
}

// pack two f32 -> one u32 of 2 bf16 (lo = a, hi = b).  Validated ONLY for
// a,b >= 0 (P values) — keep it that way.
DEV u32 cvt_pk_bf16(float a, float b) {
    u32 r;
    asm("v_cvt_pk_bf16_f32 %0, %1, %2" : "=v"(r) : "v"(a), "v"(b));
    return r;
}

// ---------------------------------------------------------------------------
// Kernel 1: weight transpose+convert.  W[c][h] f32 -> Wt[w][h][c] bf16.
// Wq pre-scaled by 1/sqrt(512)*log2(e).
// ---------------------------------------------------------------------------
__global__ __launch_bounds__(256) void prep_kernel(const float* __restrict__ W0,
                                                   const float* __restrict__ W1,
                                                   const float* __restrict__ W2,
                                                   u16* __restrict__ Wt) {
    int idx = blockIdx.x * 256 + threadIdx.x;   // 3*64*512 = 98304
    int w = idx >> 15, rem = idx & 32767, h = rem >> 9, c = rem & 511;
    const float* W = (w == 0) ? W0 : ((w == 1) ? W1 : W2);
    float v = W[c * 64 + h];
    if (w == 0) v *= 0.044194173824159216f * 1.4426950408889634f;  // SCL*log2e
    Wt[idx] = f2bf(v);
}

// ---------------------------------------------------------------------------
// Kernel 2: QKV projection via MFMA 16x16x32 bf16, reading x f32 directly
// (f2bf in-register; the 3 mats of one row-group reuse the same x slab
// through L2).  768 blocks: rg = blk/3, mat = blk%3.
// ---------------------------------------------------------------------------
__global__ __launch_bounds__(256) void proj_kernel(const float* __restrict__ x,
                                                   const u16* __restrict__ Wt,
                                                   u16* __restrict__ Q,
                                                   u16* __restrict__ Kq,
                                                   u16* __restrict__ Vt) {
    const int wave = threadIdx.x >> 6, lane = threadIdx.x & 63;
    const int lr = lane & 15, lg = lane >> 4;
    const int mat = blockIdx.x % 3;
    const int rg = blockIdx.x / 3;
    const int r0 = rg * 64 + wave * 16;
    const int grow = r0 + lr;

    f32x4 acc[4];
#pragma unroll
    for (int b = 0; b < 4; ++b) acc[b] = (f32x4){0.f, 0.f, 0.f, 0.f};

#pragma unroll
    for (int kk = 0; kk < 16; ++kk) {
        const float* xp = x + (size_t)grow * 512 + kk * 32 + lg * 8;
        float4 a0 = *reinterpret_cast<const float4*>(xp);
        float4 a1 = *reinterpret_cast<const float4*>(xp + 4);
        bf16x8 af = cvt8_rne(a0, a1);
#pragma unroll
        for (int nt = 0; nt < 4; ++nt) {
            bf16x8 bf = ld_bf8(Wt + mat * 32768 + (lr + 16 * nt) * 512 + kk * 32 + lg * 8);
            acc[nt] = __builtin_amdgcn_mfma_f32_16x16x32_bf16(af, bf, acc[nt], 0, 0, 0);
        }
    }

    if (mat < 2) {
        u16* dst = (mat == 0) ? Q : Kq;
#pragma unroll
        for (int nt = 0; nt < 4; ++nt) {
            const int h = lr + 16 * nt;
#pragma unroll
            for (int reg = 0; reg < 4; ++reg)
                dst[(size_t)(r0 + 4 * lg + reg) * 64 + h] = f2bf(acc[nt][reg]);
        }
    } else {
        const int bidx = r0 >> 12;
        const int t0 = (r0 & 4095) + 4 * lg;
#pragma unroll
        for (int nt = 0; nt < 4; ++nt) {
            const int h = lr + 16 * nt;
            ushort4 hv;
            hv.x = f2bf(acc[nt][0]); hv.y = f2bf(acc[nt][1]);
            hv.z = f2bf(acc[nt][2]); hv.w = f2bf(acc[nt][3]);
            *reinterpret_cast<ushort4*>(Vt + ((size_t)(bidx * 64 + h)) * 4096 + t0) = hv;
        }
    }
}

// ---------------------------------------------------------------------------
// Attention helpers (32x32 swapped-operand pieces; all validated in R6)
// ---------------------------------------------------------------------------
DEV f32x16 qk_sub(const u16* kp, const bf16x8 (&qf)[4]) {
    f32x16 st;
#pragma unroll
    for (int r = 0; r < 16; ++r) st[r] = 0.f;
#pragma unroll
    for (int kk = 0; kk < 4; ++kk)
        st = __builtin_amdgcn_mfma_f32_32x32x16_bf16(ld_bf8(kp + kk * 16), qf[kk], st, 0, 0, 0);
    return st;
}

DEV void mask_diag(f32x16& st, int q31, int hi) {
#pragma unroll
    for (int reg = 0; reg < 16; ++reg) {
        const int crow = (reg & 3) + 8 * (reg >> 2) + 4 * hi;
        if (crow > q31) st[reg] = -3.0e38f;
    }
}

// pairwise max tree over 16 regs (depth 4)
DEV float max16(const f32x16& a) {
    float t[8];
#pragma unroll
    for (int i = 0; i < 8; ++i) t[i] = fmaxf(a[i], a[i + 8]);
    float u0 = fmaxf(t[0], t[4]), u1 = fmaxf(t[1], t[5]);
    float u2 = fmaxf(t[2], t[6]), u3 = fmaxf(t[3], t[7]);
    return fmaxf(fmaxf(u0, u1), fmaxf(u2, u3));
}

// st = exp2(st - m); returns 4-chain partial sum
DEV float expsum(f32x16& st, float m) {
    float r0 = 0.f, r1 = 0.f, r2 = 0.f, r3 = 0.f;
#pragma unroll
    for (int g = 0; g < 4; ++g) {
        float p0 = exp2f(st[4 * g + 0] - m);
        float p1 = exp2f(st[4 * g + 1] - m);
        float p2 = exp2f(st[4 * g + 2] - m);
        float p3 = exp2f(st[4 * g + 3] - m);
        st[4 * g + 0] = p0; st[4 * g + 1] = p1;
        st[4 * g + 2] = p2; st[4 * g + 3] = p3;
        r0 += p0; r1 += p1; r2 += p2; r3 += p3;
    }
    return (r0 + r1) + (r2 + r3);
}

// P^T registers -> two B-fragments for PV.  8 cvt_pk + 4 shfl_xor + selects.
// (key map verified in R6: hi=0: pb0 = {A0,A1,pA0,pA1}; hi=1: pb0 = {pA2,pA3,A2,A3};
//  pb1 analogous with A4..A7.)
DEV void packP(const f32x16& st, bf16x8& pb0, bf16x8& pb1, int hi) {
    u32 A0 = cvt_pk_bf16(st[0], st[1]),  A1 = cvt_pk_bf16(st[2], st[3]);
    u32 A2 = cvt_pk_bf16(st[4], st[5]),  A3 = cvt_pk_bf16(st[6], st[7]);
    u32 A4 = cvt_pk_bf16(st[8], st[9]),  A5 = cvt_pk_bf16(st[10], st[11]);
    u32 A6 = cvt_pk_bf16(st[12], st[13]), A7 = cvt_pk_bf16(st[14], st[15]);
    u32 e0 = __shfl_xor(hi ? A0 : A2, 32, 64);
    u32 e1 = __shfl_xor(hi ? A1 : A3, 32, 64);
    u32 e2 = __shfl_xor(hi ? A4 : A6, 32, 64);
    u32 e3 = __shfl_xor(hi ? A5 : A7, 32, 64);
    u32x4v w0, w1;
    w0[0] = hi ? e0 : A0;
    w0[1] = hi ? e1 : A1;
    w0[2] = hi ? A2 : e0;
    w0[3] = hi ? A3 : e1;
    w1[0] = hi ? e2 : A4;
    w1[1] = hi ? e3 : A5;
    w1[2] = hi ? A6 : e2;
    w1[3] = hi ? A7 : e3;
    pb0 = __builtin_bit_cast(bf16x8, w0);
    pb1 = __builtin_bit_cast(bf16x8, w1);
}

DEV void pv(const u16* vp, const bf16x8& pb0, const bf16x8& pb1,
            f32x16& o0, f32x16& o1) {
    bf16x8 v00 = ld_bf8(vp);
    bf16x8 v01 = ld_bf8(vp + 16);
    bf16x8 v10 = ld_bf8(vp + 32 * 4096);
    bf16x8 v11 = ld_bf8(vp + 32 * 4096 + 16);
    o0 = __builtin_amdgcn_mfma_f32_32x32x16_bf16(v00, pb0, o0, 0, 0, 0);
    o0 = __builtin_amdgcn_mfma_f32_32x32x16_bf16(v01, pb1, o0, 0, 0, 0);
    o1 = __builtin_amdgcn_mfma_f32_32x32x16_bf16(v10, pb0, o1, 0, 0, 0);
    o1 = __builtin_amdgcn_mfma_f32_32x32x16_bf16(v11, pb1, o1, 0, 0, 0);
}

// ---------------------------------------------------------------------------
// Kernel 3: causal flash attention, swapped-operand 32x32, zero LDS.
// ONE WAVE PER BLOCK (64 threads): inactive chunks exit at dispatch, active
// chunks pack densely into wave slots.  Decode bijective over (tile, c):
// tile = ((bid&3)<<7)|((bid>>2)&127), c = bid>>9; b = bid&3 spreads batches
// across XCDs for K/V L2 locality.
// ---------------------------------------------------------------------------
__global__ __launch_bounds__(64) void attn_part_kernel(const u16* __restrict__ Q,
                                                       const u16* __restrict__ K,
                                                       const u16* __restrict__ Vt,
                                                       float* __restrict__ Opart,
                                                       float* __restrict__ Mpart,
                                                       float* __restrict__ Lpart,
                                                       int SPLIT, int CT) {
    const int lane = threadIdx.x;
    const int q31 = lane & 31, hi = lane >> 5;
    const int bid = blockIdx.x;
    const int tile = ((bid & 3) << 7) | ((bid >> 2) & 127);
    const int c = bid >> 9;
    const int b = tile >> 7, qi = tile & 127;
    const int qr0 = qi * 32;
    const int nkv = qi + 1;                   // 32-key subtiles for this q-tile
    const int s0 = c * CT;
    if (s0 >= nkv) return;
    const int s1 = min(nkv, s0 + CT);

    const u16* Qb = Q + (size_t)b * 4096 * 64;
    const u16* Kb = K + (size_t)b * 4096 * 64;
    const u16* Vb = Vt + (size_t)b * 64 * 4096;

    bf16x8 qf[4];
#pragma unroll
    for (int kk = 0; kk < 4; ++kk)
        qf[kk] = ld_bf8(Qb + (size_t)(qr0 + q31) * 64 + kk * 16 + hi * 8);

    f32x16 o0, o1;
#pragma unroll
    for (int r = 0; r < 16; ++r) { o0[r] = 0.f; o1[r] = 0.f; }
    float m_run = -1.0e30f, l_run = 0.f;

    for (int s = s0; s < s1; s += 2) {
        const int kv0 = s * 32;
        const bool hasB = (s + 1 < s1);
        const u16* kpA = Kb + (size_t)(kv0 + q31) * 64 + hi * 8;

        f32x16 stA = qk_sub(kpA, qf);
        f32x16 stB;
        if (hasB) stB = qk_sub(kpA + 32 * 64, qf);

        if (s == qi) mask_diag(stA, q31, hi);
        if (hasB && s + 1 == qi) mask_diag(stB, q31, hi);

        float pm = hasB ? fmaxf(max16(stA), max16(stB)) : max16(stA);
        pm = fmaxf(pm, __shfl_xor(pm, 32, 64));

        // defer-rescale (THR = 11.5 log2-units)
        if (!__all(pm - m_run <= 11.5f)) {
            float mn = fmaxf(m_run, pm);
            float al = exp2f(m_run - mn);
            m_run = mn;
            l_run *= al;
#pragma unroll
            for (int r = 0; r < 16; ++r) { o0[r] *= al; o1[r] *= al; }
        }

        float rs = expsum(stA, m_run);
        if (hasB) rs += expsum(stB, m_run);
        rs += __shfl_xor(rs, 32, 64);
        l_run += rs;

        const u16* vpA = Vb + (size_t)q31 * 4096 + kv0 + hi * 8;
        bf16x8 p0, p1;
        packP(stA, p0, p1, hi);
        pv(vpA, p0, p1, o0, o1);
        if (hasB) {
            packP(stB, p0, p1, hi);
            pv(vpA + 32, p0, p1, o0, o1);
        }
    }

    // write transposed partials: Opart[base][d][q]  (coalesced: lanes = q)
    const size_t base = (size_t)(tile * SPLIT + c);
    float* Op = Opart + base * 2048;
#pragma unroll
    for (int reg = 0; reg < 16; ++reg) {
        const int crow = (reg & 3) + 8 * (reg >> 2) + 4 * hi;
        Op[crow * 32 + q31] = o0[reg];
        Op[(32 + crow) * 32 + q31] = o1[reg];
    }
    if (lane < 32) {
        Mpart[base * 32 + lane] = m_run;
        Lpart[base * 32 + lane] = l_run;
    }
}

// ---------------------------------------------------------------------------
// Kernel 4: merge partials.  One block per q-tile (512 blocks).
// LDS-staged transpose: global reads float4-coalesced, pad 33 kills bank
// conflicts, out writes coalesced.
// ---------------------------------------------------------------------------
__global__ __launch_bounds__(256) void merge_kernel(const float* __restrict__ Opart,
                                                    const float* __restrict__ Mpart,
                                                    const float* __restrict__ Lpart,
                                                    float* __restrict__ out,
                                                    int SPLIT, int CT) {
    __shared__ float ld[64 * 33];
    const int tile = blockIdx.x;            // 0..511
    const int tid = threadIdx.x;
    const int q = tid >> 3, dg = tid & 7;
    const int qi = tile & 127;
    const int nkv = qi + 1;
    int nc = (nkv + CT - 1) / CT;
    if (nc > SPLIT) nc = SPLIT;

    float M = -3.0e38f;
    for (int c = 0; c < nc; ++c)
        M = fmaxf(M, Mpart[(tile * SPLIT + c) * 32 + q]);

    float L = 0.f;
    float acc[8];
#pragma unroll
    for (int j = 0; j < 8; ++j) acc[j] = 0.f;

    for (int c = 0; c < nc; ++c) {
        const size_t base = (size_t)(tile * SPLIT + c);
        const float4* src = reinterpret_cast<const float4*>(Opart + base * 2048);
        float4 v0 = src[tid * 2];
        float4 v1 = src[tid * 2 + 1];
        {
            const int drow = tid >> 2;
            const int qq = (tid & 3) * 8;
            float* dst = &ld[drow * 33 + qq];
            dst[0] = v0.x; dst[1] = v0.y; dst[2] = v0.z; dst[3] = v0.w;
            dst[4] = v1.x; dst[5] = v1.y; dst[6] = v1.z; dst[7] = v1.w;
        }
        __syncthreads();
        float w = exp2f(Mpart[base * 32 + q] - M);
        L += w * Lpart[base * 32 + q];
#pragma unroll
        for (int j = 0; j < 8; ++j)
            acc[j] += w * ld[(dg * 8 + j) * 33 + q];
        __syncthreads();
    }

    const float inv = 1.0f / L;
    float4 r0, r1;
    r0.x = acc[0] * inv; r0.y = acc[1] * inv; r0.z = acc[2] * inv; r0.w = acc[3] * inv;
    r1.x = acc[4] * inv; r1.y = acc[5] * inv; r1.z = acc[6] * inv; r1.w = acc[7] * inv;
    float4* dst = reinterpret_cast<float4*>(out + ((size_t)(tile * 32 + q)) * 64 + dg * 8);
    dst[0] = r0;
    dst[1] = r1;
}

// ---------------------------------------------------------------------------
extern "C" void kernel_launch(void* const* d_in, const int* in_sizes, int n_in,
                              void* d_out, int out_size, void* d_ws, size_t ws_size,
                              hipStream_t stream) {
    const float* x  = (const float*)d_in[0];
    const float* Wq = (const float*)d_in[1];
    const float* Wk = (const float*)d_in[2];
    const float* Wv = (const float*)d_in[3];
    float* out = (float*)d_out;

    char* ws = (char*)d_ws;
    const size_t MB = 1024 * 1024;
    u16* Qw  = (u16*)(ws);                     // 2 MiB
    u16* Kw  = (u16*)(ws + 2 * MB);            // 2 MiB
    u16* Vtw = (u16*)(ws + 4 * MB);            // 2 MiB
    u16* Wt  = (u16*)(ws + 6 * MB);            // 96 KiB

    int SPLIT = 16;
    while (SPLIT > 1) {
        size_t need = 8 * MB + (size_t)SPLIT * 4 * MB + (size_t)SPLIT * 128 * 1024;
        if (need <= ws_size) break;
        SPLIT >>= 1;
    }
    const int CT = (128 + SPLIT - 1) / SPLIT;

    float* Opart = (float*)(ws + 8 * MB);
    float* Mpart = (float*)(ws + 8 * MB + (size_t)SPLIT * 4 * MB);
    float* Lpart = Mpart + (size_t)SPLIT * 512 * 32;

    prep_kernel<<<384, 256, 0, stream>>>(Wq, Wk, Wv, Wt);
    proj_kernel<<<768, 256, 0, stream>>>(x, Wt, Qw, Kw, Vtw);
    attn_part_kernel<<<512 * SPLIT, 64, 0, stream>>>(Qw, Kw, Vtw, Opart, Mpart, Lpart,
                                                     SPLIT, CT);
    merge_kernel<<<512, 256, 0, stream>>>(Opart, Mpart, Lpart, out, SPLIT, CT);
}